// Round 1
// baseline (686.160 us; speedup 1.0000x reference)
//
#include <hip/hip_runtime.h>
#include <stdint.h>

#define BB 32
#define CC 256
#define HH 56
#define WW 56
#define GG 4           // 4 x u64 channel groups (256 = 4*64)
#define TAPS 9
#define NCONV 3
#define BN_EPS 1e-5f

// workspace layout (bytes):
//   abits : BB*HH*GG*WW u64 = 401408 * 8 = 3,211,264
//   wbits : NCONV*TAPS*GG*CC u64 = 27648 * 8 = 221,184
//   scales: NCONV*CC f32 = 3,072
// total ~3.44 MB
#define ABITS_WORDS ((size_t)BB * HH * GG * WW)
#define WBITS_WORDS ((size_t)NCONV * TAPS * GG * CC)

// ---------------------------------------------------------------------------
// Kernel 1: pack activation signs. wave = (n, h, g); lane = channel in group.
// bit = (x + bias0) > 0  (sign==0 treated as -1; error ~scale ~5e-4, negligible)
// abits layout: [n][h][g][w]
// ---------------------------------------------------------------------------
__global__ __launch_bounds__(256) void pack_act_kernel(
    const float* __restrict__ x, const float* __restrict__ bias0,
    uint64_t* __restrict__ abits)
{
    const int lane = threadIdx.x & 63;
    const int wid  = blockIdx.x * 4 + (threadIdx.x >> 6);   // 0 .. 32*56*4-1
    const int g  = wid & 3;
    const int nh = wid >> 2;            // n*56 + h
    const int h  = nh % HH;
    const int n  = nh / HH;
    const int c  = g * 64 + lane;
    const float b = bias0[c];
    const float* row = x + ((size_t)(n * CC + c) * HH + h) * WW;
    uint64_t* orow = abits + ((size_t)(n * HH + h) * GG + g) * WW;
    for (int w = 0; w < WW; ++w) {
        float v = row[w] + b;
        uint64_t m = __ballot(v > 0.0f);
        if (lane == 0) orow[w] = m;
    }
}

// ---------------------------------------------------------------------------
// Kernel 2: per-conv weight sign bits + per-output-channel scale (mean |w|).
// one wave per (j, o). wbits layout: [j][t][g][o]  (o contiguous -> coalesced)
// ---------------------------------------------------------------------------
__global__ __launch_bounds__(64) void pack_w_kernel(
    const float* __restrict__ w0, const float* __restrict__ w1,
    const float* __restrict__ w2,
    uint64_t* __restrict__ wbits, float* __restrict__ scales)
{
    const int j = blockIdx.x >> 8;          // 0..2
    const int o = blockIdx.x & 255;
    const float* wp = (j == 0) ? w0 : ((j == 1) ? w1 : w2);
    const int lane = threadIdx.x;           // 0..63
    const float* wo = wp + (size_t)o * CC * TAPS;
    float s = 0.f;
    for (int k = lane; k < CC * TAPS; k += 64) s += fabsf(wo[k]);
    #pragma unroll
    for (int d = 32; d > 0; d >>= 1) s += __shfl_xor(s, d);
    if (lane == 0) scales[j * CC + o] = s * (1.0f / (float)(CC * TAPS));

    for (int t = 0; t < TAPS; ++t) {
        #pragma unroll
        for (int g = 0; g < GG; ++g) {
            float v = wp[((size_t)o * CC + g * 64 + lane) * TAPS + t];
            uint64_t m = __ballot(v > 0.0f);
            if (lane == 0) wbits[((size_t)(j * TAPS + t) * GG + g) * CC + o] = m;
        }
    }
}

// ---------------------------------------------------------------------------
// Kernel 3: binary conv x3 (with shift4 rolls) + BN + residual + PReLU.
// wave = (n, h, wc) covering 8 pixels (w = wc*8 .. wc*8+7), all 256 o in
// 4 chunks of 64 (lane = o within chunk).
//   activation words: wave-uniform address -> scalar loads
//   weight words:     lane-consecutive in o -> coalesced vector loads
// dot_j(o,p) = 256*nvalid(p) - 2 * sum popcount(a ^ w); out = scale_j[o]*dot.
// ---------------------------------------------------------------------------
__global__ __launch_bounds__(256) void conv_main_kernel(
    const uint64_t* __restrict__ abits, const uint64_t* __restrict__ wbits,
    const float* __restrict__ scales, const float* __restrict__ x,
    const float* __restrict__ gamma, const float* __restrict__ beta,
    const float* __restrict__ rmean, const float* __restrict__ rvar,
    const float* __restrict__ bias1, const float* __restrict__ prelu_a,
    const float* __restrict__ bias2, float* __restrict__ out)
{
    const int lane = threadIdx.x & 63;
    int gwid = blockIdx.x * 4 + (threadIdx.x >> 6);      // 0 .. 32*56*7-1
    gwid = __builtin_amdgcn_readfirstlane(gwid);          // force uniformity
    const int wc  = gwid % 7;
    const int h   = (gwid / 7) % HH;
    const int n   = gwid / (7 * HH);
    const int w0p = wc * 8;

    // valid-tap count per pixel (same for all 3 convs: bounds are pre-roll)
    int nv[8];
    #pragma unroll
    for (int p = 0; p < 8; ++p) nv[p] = 0;
    for (int t = 0; t < TAPS; ++t) {
        const int dy = t / 3 - 1, dx = t % 3 - 1;
        const int hy = h + dy;
        if (hy < 0 || hy >= HH) continue;
        #pragma unroll
        for (int p = 0; p < 8; ++p) {
            const int wx = w0p + p + dx;
            if (wx >= 0 && wx < WW) nv[p]++;
        }
    }

    float fsum[4][8];
    #pragma unroll
    for (int oc = 0; oc < 4; ++oc)
        #pragma unroll
        for (int p = 0; p < 8; ++p) fsum[oc][p] = 0.f;

    for (int j = 0; j < NCONV; ++j) {
        const int amt = (j == 0) ? 0 : ((j == 1) ? 1 : 3);
        uint32_t acc[4][8];
        #pragma unroll
        for (int oc = 0; oc < 4; ++oc)
            #pragma unroll
            for (int p = 0; p < 8; ++p) acc[oc][p] = 0u;

        for (int t = 0; t < TAPS; ++t) {
            const int dy = t / 3 - 1, dx = t % 3 - 1;
            const int hy = h + dy;
            if (hy < 0 || hy >= HH) continue;   // zero-padded row: no contribution
            #pragma unroll
            for (int g = 0; g < GG; ++g) {
                // shift4 roll offsets: roll(+amt) reads src at (idx - amt) mod N
                int rH = 0, rW = 0;
                if (j > 0) {
                    if (g == 0) rH = -amt; else if (g == 1) rH = amt;
                    else if (g == 2) rW = -amt; else rW = amt;
                }
                int ha = hy + rH;
                if (ha < 0) ha += HH; else if (ha >= HH) ha -= HH;
                const uint64_t* arow = abits + ((size_t)(n * HH + ha) * GG + g) * WW;

                uint64_t aw[8];   // wave-uniform -> SGPRs via s_load
                #pragma unroll
                for (int p = 0; p < 8; ++p) {
                    int wa = w0p + p + dx + rW;
                    if (wa < 0) wa += WW; else if (wa >= WW) wa -= WW;
                    aw[p] = arow[wa];
                }

                const uint64_t* wrow = wbits + ((size_t)(j * TAPS + t) * GG + g) * CC;
                #pragma unroll
                for (int oc = 0; oc < 4; ++oc) {
                    const uint64_t wv = wrow[oc * 64 + lane];
                    #pragma unroll
                    for (int p = 0; p < 8; ++p) {
                        const int wx = w0p + p + dx;
                        if (wx >= 0 && wx < WW)           // block-uniform branch
                            acc[oc][p] += (uint32_t)__popcll(aw[p] ^ wv);
                    }
                }
            }
        }
        #pragma unroll
        for (int oc = 0; oc < 4; ++oc) {
            const float sc = scales[j * CC + oc * 64 + lane];
            #pragma unroll
            for (int p = 0; p < 8; ++p)
                fsum[oc][p] += sc * (float)(CC * nv[p] - 2 * (int)acc[oc][p]);
        }
    }

    // epilogue: BN(inference) + residual + bias1 -> PReLU -> + bias2
    #pragma unroll
    for (int oc = 0; oc < 4; ++oc) {
        const int o = oc * 64 + lane;
        const float inv = gamma[o] * rsqrtf(rvar[o] + BN_EPS);
        const float mu = rmean[o], bt = beta[o];
        const float b1 = bias1[o], pa = prelu_a[o], b2 = bias2[o];
        const size_t base = ((size_t)(n * CC + o) * HH + h) * WW + w0p;
        #pragma unroll
        for (int p = 0; p < 8; ++p) {
            float v = (fsum[oc][p] - mu) * inv + bt + x[base + p] + b1;
            v = (v > 0.f) ? v : pa * v;
            out[base + p] = v + b2;
        }
    }
}

// ---------------------------------------------------------------------------
extern "C" void kernel_launch(void* const* d_in, const int* in_sizes, int n_in,
                              void* d_out, int out_size, void* d_ws, size_t ws_size,
                              hipStream_t stream) {
    const float* x       = (const float*)d_in[0];
    const float* bias0   = (const float*)d_in[1];
    const float* w0      = (const float*)d_in[2];
    const float* w1      = (const float*)d_in[3];
    const float* w2      = (const float*)d_in[4];
    const float* gamma   = (const float*)d_in[5];
    const float* beta    = (const float*)d_in[6];
    const float* rmean   = (const float*)d_in[7];
    const float* rvar    = (const float*)d_in[8];
    const float* bias1   = (const float*)d_in[9];
    const float* prelu_a = (const float*)d_in[10];
    const float* bias2   = (const float*)d_in[11];
    float* out = (float*)d_out;

    uint64_t* abits  = (uint64_t*)d_ws;
    uint64_t* wbits  = abits + ABITS_WORDS;
    float*    scales = (float*)(wbits + WBITS_WORDS);

    // kernel 1: 32*56*4 waves, 4 waves/block
    pack_act_kernel<<<dim3(BB * HH * GG / 4), dim3(256), 0, stream>>>(x, bias0, abits);
    // kernel 2: one 64-thread wave per (conv, out-channel)
    pack_w_kernel<<<dim3(NCONV * CC), dim3(64), 0, stream>>>(w0, w1, w2, wbits, scales);
    // kernel 3: 32*56*7 waves, 4 waves/block
    conv_main_kernel<<<dim3(BB * HH * 7 / 4), dim3(256), 0, stream>>>(
        abits, wbits, scales, x, gamma, beta, rmean, rvar, bias1, prelu_a, bias2, out);
}

// Round 2
// 482.062 us; speedup vs baseline: 1.4234x; 1.4234x over previous
//
#include <hip/hip_runtime.h>
#include <stdint.h>

#define BB 32
#define CC 256
#define HH 56
#define WW 56
#define GG 4           // 4 x u64 channel groups (256 = 4*64)
#define TAPS 9
#define NCONV 3
#define PW 58          // padded row width in words (zero col at 0 and 57)
#define NPLANE 12      // (j,g) combos, rolls baked in
#define BN_EPS 1e-5f

// workspace layout (u64 words unless noted):
//   planes : [n][12][56][58]   = 32*12*56*58      = 1,247,232 w  (9.98 MB)
//   wb2    : [108][64][4]      = 108*256          = 27,648 w     (216 KB)
//            (combo=(j*9+t)*4+g; [lane][oc] so each lane's 4 words are 32B)
//   scales : [3][256] f32                                         (3 KB)
//   Cw     : [27][256] f32  (Cw[j*9+t][o] = 256 - 2*sum_g popc(w))  (27 KB)
#define PLANE_N_WORDS ((size_t)NPLANE * HH * PW)
#define PLANES_WORDS  ((size_t)BB * PLANE_N_WORDS)
#define WB2_WORDS     ((size_t)108 * 64 * 4)

// ---------------------------------------------------------------------------
// Kernel 1: pack activation signs, transposed (lane = w -> coalesced x loads),
// write 12 pre-rolled zero-padded bit-planes.
// wave = (n,h,g); lane w in [0,55] holds the u64 for its pixel column.
// ---------------------------------------------------------------------------
__global__ __launch_bounds__(256) void pack_act_kernel(
    const float* __restrict__ x, const float* __restrict__ bias0,
    uint64_t* __restrict__ planes)
{
    const int lane = threadIdx.x & 63;
    const int wid  = blockIdx.x * 4 + (threadIdx.x >> 6);   // 0 .. 32*56*4-1
    const int g  = wid & 3;
    const int nh = wid >> 2;
    const int h  = nh % HH;
    const int n  = nh / HH;
    const int w  = lane;
    const int wl = (w < WW) ? w : (WW - 1);   // clamp lanes 56..63 (avoid OOB)

    const float* xp = x + ((size_t)(n * CC + g * 64) * HH + h) * WW;
    uint32_t mlo = 0u, mhi = 0u;
    #pragma unroll
    for (int c = 0; c < 32; ++c) {
        float v = xp[(size_t)c * (HH * WW) + wl] + bias0[g * 64 + c];
        mlo |= (v > 0.f ? 1u : 0u) << c;
    }
    #pragma unroll
    for (int c = 0; c < 32; ++c) {
        float v = xp[(size_t)(c + 32) * (HH * WW) + wl] + bias0[g * 64 + c + 32];
        mhi |= (v > 0.f ? 1u : 0u) << c;
    }
    const uint64_t m = ((uint64_t)mhi << 32) | (uint64_t)mlo;

    // write the 3 conv copies for this group, rolls baked, plus zero pads
    #pragma unroll 1
    for (int j = 0; j < NCONV; ++j) {
        const int amt = (j == 0) ? 0 : ((j == 1) ? 1 : 3);
        const int AH = (g == 0) ? amt : ((g == 1) ? -amt : 0);
        const int AW = (g == 2) ? amt : ((g == 3) ? -amt : 0);
        int row = h + AH; if (row < 0) row += HH; else if (row >= HH) row -= HH;
        uint64_t* prow = planes + ((size_t)(n * NPLANE + j * 4 + g) * HH + row) * PW;
        if (w < WW) {
            int col = w + AW; if (col < 0) col += WW; else if (col >= WW) col -= WW;
            prow[col + 1] = m;
        } else if (w == 56) {
            prow[0] = 0ull;          // left pad
        } else if (w == 57) {
            prow[PW - 1] = 0ull;     // right pad
        }
    }
}

// ---------------------------------------------------------------------------
// Kernel 2: weight sign bits (repacked [combo][lane][oc]), per-o scale,
// and pad-correction constants Cw[j*9+t][o] = 256 - 2*sum_g popc(w).
// one wave per (j, o).
// ---------------------------------------------------------------------------
__global__ __launch_bounds__(64) void pack_w_kernel(
    const float* __restrict__ w0, const float* __restrict__ w1,
    const float* __restrict__ w2,
    uint64_t* __restrict__ wb2, float* __restrict__ scales,
    float* __restrict__ Cw)
{
    const int j = blockIdx.x >> 8;          // 0..2
    const int o = blockIdx.x & 255;
    const float* wp = (j == 0) ? w0 : ((j == 1) ? w1 : w2);
    const int lane = threadIdx.x;           // 0..63

    const float* wo = wp + (size_t)o * CC * TAPS;
    float s = 0.f;
    for (int k = lane; k < CC * TAPS; k += 64) s += fabsf(wo[k]);
    #pragma unroll
    for (int d = 32; d > 0; d >>= 1) s += __shfl_xor(s, d);
    if (lane == 0) scales[j * CC + o] = s * (1.0f / (float)(CC * TAPS));

    for (int t = 0; t < TAPS; ++t) {
        int pcsum = 0;
        #pragma unroll
        for (int g = 0; g < GG; ++g) {
            float v = wp[((size_t)o * CC + g * 64 + lane) * TAPS + t];
            uint64_t m = __ballot(v > 0.0f);
            pcsum += (int)__popcll(m);
            if (lane == 0)
                wb2[(((size_t)(j * TAPS + t) * GG + g) * 64 + (o & 63)) * 4 + (o >> 6)] = m;
        }
        if (lane == 0) Cw[(j * TAPS + t) * CC + o] = (float)(256 - 2 * pcsum);
    }
}

// ---------------------------------------------------------------------------
// Kernel 3: binary conv x3 + BN + residual + PReLU. Guard-free inner loop:
// pre-rolled zero-padded planes -> 8 consecutive uniform a-word loads per
// (j,t,g); weights 2x dwordx4 per (j,t,g); pure xor+bcnt accumulation.
// H-invalid rows skipped by uniform branch; W-pad words corrected via Cw.
// ---------------------------------------------------------------------------
__global__ __launch_bounds__(256) void conv_main_kernel(
    const uint64_t* __restrict__ planes, const uint64_t* __restrict__ wb2,
    const float* __restrict__ scales, const float* __restrict__ Cw,
    const float* __restrict__ x,
    const float* __restrict__ gamma, const float* __restrict__ beta,
    const float* __restrict__ rmean, const float* __restrict__ rvar,
    const float* __restrict__ bias1, const float* __restrict__ prelu_a,
    const float* __restrict__ bias2, float* __restrict__ out)
{
    const int lane = threadIdx.x & 63;
    int gwid = blockIdx.x * 4 + (threadIdx.x >> 6);      // 0 .. 32*56*7-1
    gwid = __builtin_amdgcn_readfirstlane(gwid);          // force uniformity
    const int wc  = gwid % 7;
    const int h   = (gwid / 7) % HH;
    const int n   = gwid / (7 * HH);
    const int w0p = wc * 8;
    const int NR  = 3 - (h == 0) - (h == HH - 1);        // valid tap rows
    const bool edgeL = (wc == 0), edgeR = (wc == 6);

    float fsum[4][8];
    #pragma unroll
    for (int oc = 0; oc < 4; ++oc)
        #pragma unroll
        for (int p = 0; p < 8; ++p) fsum[oc][p] = 0.f;

    #pragma unroll 1
    for (int j = 0; j < NCONV; ++j) {
        uint32_t acc[4][8];
        #pragma unroll
        for (int oc = 0; oc < 4; ++oc)
            #pragma unroll
            for (int p = 0; p < 8; ++p) acc[oc][p] = 0u;

        #pragma unroll 1
        for (int ty = 0; ty < 3; ++ty) {
            const int hy = h + ty - 1;
            if (hy < 0 || hy >= HH) continue;            // uniform scalar branch
            #pragma unroll 1
            for (int tx = 0; tx < 3; ++tx) {
                const int t = ty * 3 + tx;
                #pragma unroll
                for (int g = 0; g < GG; ++g) {
                    const uint64_t* rowp = planes +
                        ((size_t)(n * NPLANE + j * 4 + g) * HH + hy) * PW + (w0p + tx);
                    uint64_t aw[8];                      // wave-uniform -> SGPRs
                    #pragma unroll
                    for (int p = 0; p < 8; ++p) aw[p] = rowp[p];

                    const uint64_t* wl = wb2 +
                        (((size_t)(j * TAPS + t) * GG + g) * 64 + lane) * 4;
                    #pragma unroll
                    for (int oc = 0; oc < 4; ++oc) {
                        const uint64_t wv = wl[oc];
                        #pragma unroll
                        for (int p = 0; p < 8; ++p)
                            acc[oc][p] += (uint32_t)__popcll(aw[p] ^ wv);
                    }
                }
            }
        }

        // fold: dot = 768*NR - 2*acc  (minus W-edge pad corrections), * scale
        #pragma unroll
        for (int oc = 0; oc < 4; ++oc) {
            const int o = oc * 64 + lane;
            const float sc = scales[j * CC + o];
            float dot[8];
            #pragma unroll
            for (int p = 0; p < 8; ++p)
                dot[p] = (float)(768 * NR - 2 * (int)acc[oc][p]);
            if (edgeL) {
                float c = 0.f;
                #pragma unroll
                for (int ty = 0; ty < 3; ++ty) {
                    const int hy = h + ty - 1;
                    if (hy >= 0 && hy < HH) c += Cw[(j * TAPS + ty * 3 + 0) * CC + o];
                }
                dot[0] -= c;
            }
            if (edgeR) {
                float c = 0.f;
                #pragma unroll
                for (int ty = 0; ty < 3; ++ty) {
                    const int hy = h + ty - 1;
                    if (hy >= 0 && hy < HH) c += Cw[(j * TAPS + ty * 3 + 2) * CC + o];
                }
                dot[7] -= c;
            }
            #pragma unroll
            for (int p = 0; p < 8; ++p) fsum[oc][p] += sc * dot[p];
        }
    }

    // epilogue: BN(inference) + residual + bias1 -> PReLU -> + bias2
    #pragma unroll
    for (int oc = 0; oc < 4; ++oc) {
        const int o = oc * 64 + lane;
        const float inv = gamma[o] * rsqrtf(rvar[o] + BN_EPS);
        const float mu = rmean[o], bt = beta[o];
        const float b1 = bias1[o], pa = prelu_a[o], b2 = bias2[o];
        const size_t base = ((size_t)(n * CC + o) * HH + h) * WW + w0p;
        #pragma unroll
        for (int p = 0; p < 8; ++p) {
            float v = (fsum[oc][p] - mu) * inv + bt + x[base + p] + b1;
            v = (v > 0.f) ? v : pa * v;
            out[base + p] = v + b2;
        }
    }
}

// ---------------------------------------------------------------------------
extern "C" void kernel_launch(void* const* d_in, const int* in_sizes, int n_in,
                              void* d_out, int out_size, void* d_ws, size_t ws_size,
                              hipStream_t stream) {
    const float* x       = (const float*)d_in[0];
    const float* bias0   = (const float*)d_in[1];
    const float* w0      = (const float*)d_in[2];
    const float* w1      = (const float*)d_in[3];
    const float* w2      = (const float*)d_in[4];
    const float* gamma   = (const float*)d_in[5];
    const float* beta    = (const float*)d_in[6];
    const float* rmean   = (const float*)d_in[7];
    const float* rvar    = (const float*)d_in[8];
    const float* bias1   = (const float*)d_in[9];
    const float* prelu_a = (const float*)d_in[10];
    const float* bias2   = (const float*)d_in[11];
    float* out = (float*)d_out;

    uint64_t* planes = (uint64_t*)d_ws;
    uint64_t* wb2    = planes + PLANES_WORDS;
    float*    scales = (float*)(wb2 + WB2_WORDS);
    float*    Cw     = scales + NCONV * CC;

    // kernel 1: 32*56*4 waves, 4 waves/block
    pack_act_kernel<<<dim3(BB * HH * GG / 4), dim3(256), 0, stream>>>(x, bias0, planes);
    // kernel 2: one 64-thread wave per (conv, out-channel)
    pack_w_kernel<<<dim3(NCONV * CC), dim3(64), 0, stream>>>(w0, w1, w2, wb2, scales, Cw);
    // kernel 3: 32*56*7 waves, 4 waves/block
    conv_main_kernel<<<dim3(BB * HH * 7 / 4), dim3(256), 0, stream>>>(
        planes, wb2, scales, Cw, x, gamma, beta, rmean, rvar, bias1, prelu_a, bias2, out);
}